// Round 3
// baseline (169.929 us; speedup 1.0000x reference)
//
#include <hip/hip_runtime.h>
#include <hip/hip_bf16.h>

typedef __attribute__((ext_vector_type(8))) short short8;
typedef __attribute__((ext_vector_type(4))) float f32x4;

#define B_SZ 32
#define T_SZ 4096
#define H_SZ 512
#define NROWS (B_SZ * T_SZ)   // 131072

// packed fp32x2 -> bf16x2 (RNE), single v_cvt_pk_bf16_f32: a->low16, b->high16
static __device__ __forceinline__ unsigned int pack2(float a, float b) {
  unsigned int r;
  asm("v_cvt_pk_bf16_f32 %0, %1, %2" : "=v"(r) : "v"(a), "v"(b));
  return r;
}

// branch-free tanh, exact saturation at +/-inf: 1 - 2/(e^{2x}+1)
static __device__ __forceinline__ float fast_tanh(float x) {
  float e = __expf(2.0f * x);
  return 1.0f - 2.0f / (e + 1.0f);
}

// ---- W fp32 (512x512) -> bf16 in MFMA-fragment order ----
// fragment s = grow*64 + kt*4 + kslot; holds W[grow][kt*32 + kslot*8 .. +8]
// dst uint4 index = nb*1024 + kt*64 + (kslot*16 + g); a 16-g chunk = 16 KB contiguous
__global__ __launch_bounds__(256) void prep_w_kernel(
    const float* __restrict__ W, uint4* __restrict__ Wfrag) {
  int s = blockIdx.x * 256 + threadIdx.x;   // 0..32767
  int grow  = s >> 6;
  int kt    = (s >> 2) & 15;
  int kslot = s & 3;
  const float4* Wf4 = reinterpret_cast<const float4*>(W);
  float4 lo = Wf4[grow * 128 + kt * 8 + kslot * 2];
  float4 hi = Wf4[grow * 128 + kt * 8 + kslot * 2 + 1];
  uint4 u;
  u.x = pack2(lo.x, lo.y); u.y = pack2(lo.z, lo.w);
  u.z = pack2(hi.x, hi.y); u.w = pack2(hi.z, hi.w);
  int nb = grow >> 4, g = grow & 15;
  Wfrag[nb * 1024 + kt * 64 + kslot * 16 + g] = u;
}

// ---- scores[row] = sum_g v[g] * tanh( X[row,:] . W[g,:] ) ----
// 256 thr = 4 waves, wave owns 32 rows (2 A-fragsets) -> block M=128, grid 1024.
// A in registers full-K; B double-buffered 16 KB LDS chunks via global_load_lds.
__global__ __launch_bounds__(256, 3) void score_kernel(
    const float* __restrict__ X, const uint4* __restrict__ Wfrag,
    const float* __restrict__ v, float* __restrict__ scores) {
  __shared__ unsigned char WsB[2][16384];

  const int tid   = threadIdx.x;
  const int lane  = tid & 63;
  const int wave  = tid >> 6;
  const int frow  = lane & 15;   // A: m row / B: g col
  const int kslot = lane >> 4;
  const size_t rowbase = (size_t)blockIdx.x * 128;

  // prologue: stage chunk 0 into buf 0 (16 KB linear, 4 KB per wave) — hides
  // under the A-load/convert phase below
  {
    const char* src = (const char*)Wfrag + wave * 4096 + lane * 16;
    unsigned char* dst = &WsB[0][wave * 4096];
    #pragma unroll
    for (int i = 0; i < 4; ++i)
      __builtin_amdgcn_global_load_lds((const unsigned int*)(src + i * 1024),
                                       (unsigned int*)(dst + i * 1024), 16, 0, 0);
  }

  // A fragments for 2 row-sets: X[arow][kt*32 + kslot*8 .. +8], bf16-packed
  short8 afrag0[16], afrag1[16];
  {
    const float4* xr0 = reinterpret_cast<const float4*>(X + (rowbase + wave * 32 + frow) * H_SZ);
    const float4* xr1 = reinterpret_cast<const float4*>(X + (rowbase + wave * 32 + 16 + frow) * H_SZ);
    #pragma unroll
    for (int kt = 0; kt < 16; ++kt) {
      float4 lo0 = xr0[kt * 8 + kslot * 2];
      float4 hi0 = xr0[kt * 8 + kslot * 2 + 1];
      union { uint4 u; short8 s; } c0;
      c0.u.x = pack2(lo0.x, lo0.y); c0.u.y = pack2(lo0.z, lo0.w);
      c0.u.z = pack2(hi0.x, hi0.y); c0.u.w = pack2(hi0.z, hi0.w);
      afrag0[kt] = c0.s;
      float4 lo1 = xr1[kt * 8 + kslot * 2];
      float4 hi1 = xr1[kt * 8 + kslot * 2 + 1];
      union { uint4 u; short8 s; } c1;
      c1.u.x = pack2(lo1.x, lo1.y); c1.u.y = pack2(lo1.z, lo1.w);
      c1.u.z = pack2(hi1.x, hi1.y); c1.u.w = pack2(hi1.z, hi1.w);
      afrag1[kt] = c1.s;
    }
  }
  __syncthreads();   // chunk 0 staged (drains vmcnt), A ready

  float red0[4] = {0.f, 0.f, 0.f, 0.f};
  float red1[4] = {0.f, 0.f, 0.f, 0.f};
  int cur = 0;
  for (int nb = 0; nb < 32; ++nb) {
    if (nb < 31) {   // stage next chunk into the other buffer
      const char* src = (const char*)Wfrag + (size_t)(nb + 1) * 16384 + wave * 4096 + lane * 16;
      unsigned char* dst = &WsB[cur ^ 1][wave * 4096];
      #pragma unroll
      for (int i = 0; i < 4; ++i)
        __builtin_amdgcn_global_load_lds((const unsigned int*)(src + i * 1024),
                                         (unsigned int*)(dst + i * 1024), 16, 0, 0);
    }
    float vg = v[nb * 16 + frow];

    f32x4 acc0 = {0.f, 0.f, 0.f, 0.f};
    f32x4 acc1 = {0.f, 0.f, 0.f, 0.f};
    const unsigned char* bbase = &WsB[cur][lane * 16];
    #pragma unroll
    for (int kt = 0; kt < 16; ++kt) {
      short8 b = *reinterpret_cast<const short8*>(bbase + kt * 1024);  // linear, conflict-free
      acc0 = __builtin_amdgcn_mfma_f32_16x16x32_bf16(afrag0[kt], b, acc0, 0, 0, 0);
      acc1 = __builtin_amdgcn_mfma_f32_16x16x32_bf16(afrag1[kt], b, acc1, 0, 0, 0);
    }
    // D[m][n]: n = frow (g), m = kslot*4 + reg
    #pragma unroll
    for (int r = 0; r < 4; ++r) {
      red0[r] = fmaf(vg, fast_tanh(acc0[r]), red0[r]);
      red1[r] = fmaf(vg, fast_tanh(acc1[r]), red1[r]);
    }

    __syncthreads();   // drains stage vmcnt; next buffer ready
    cur ^= 1;
  }

  // reduce over the 16 g-lanes (frow) within each kslot group
  #pragma unroll
  for (int r = 0; r < 4; ++r) {
    #pragma unroll
    for (int d = 1; d < 16; d <<= 1) {
      red0[r] += __shfl_xor(red0[r], d);
      red1[r] += __shfl_xor(red1[r], d);
    }
  }
  if (frow == 0) {
    float* sp = scores + rowbase + wave * 32 + kslot * 4;
    sp[0]  = red0[0]; sp[1]  = red0[1]; sp[2]  = red0[2]; sp[3]  = red0[3];
    sp[16] = red1[0]; sp[17] = red1[1]; sp[18] = red1[2]; sp[19] = red1[3];
  }
}

// ---- per-b softmax stats; rewrites scores in place with unnormalized exp ----
__global__ __launch_bounds__(256) void softmax_kernel(
    float* __restrict__ scores, float* __restrict__ denom) {
  const int b = blockIdx.x;
  float* s = scores + b * T_SZ;
  const int tid = threadIdx.x;
  __shared__ float redm[4], reds[4];

  float m = -1e30f;
  for (int t = tid; t < T_SZ; t += 256) m = fmaxf(m, s[t]);
  #pragma unroll
  for (int d = 1; d < 64; d <<= 1) m = fmaxf(m, __shfl_xor(m, d));
  if ((tid & 63) == 0) redm[tid >> 6] = m;
  __syncthreads();
  m = fmaxf(fmaxf(redm[0], redm[1]), fmaxf(redm[2], redm[3]));

  float sum = 0.f;
  for (int t = tid; t < T_SZ; t += 256) {
    float u = __expf(s[t] - m);
    s[t] = u;
    sum += u;
  }
  #pragma unroll
  for (int d = 1; d < 64; d <<= 1) sum += __shfl_xor(sum, d);
  if ((tid & 63) == 0) reds[tid >> 6] = sum;
  __syncthreads();
  if (tid == 0) denom[b] = reds[0] + reds[1] + reds[2] + reds[3];
}

// ---- partial[b][ch][h] = sum_{t in chunk} u_t * x[b,t,h] ----
__global__ __launch_bounds__(256) void wsum_kernel(
    const float* __restrict__ X, const float* __restrict__ u,
    float* __restrict__ partial) {
  const int ch = blockIdx.x;   // 32 chunks of 128 t
  const int b  = blockIdx.y;   // 32
  const float* xb = X + ((size_t)b * T_SZ + ch * 128) * H_SZ;
  const float* ub = u + b * T_SZ + ch * 128;
  const int h2 = threadIdx.x;  // float2 index
  float ax = 0.f, ay = 0.f;
  for (int tt = 0; tt < 128; ++tt) {
    float w = ub[tt];
    float2 xv = reinterpret_cast<const float2*>(xb + (size_t)tt * H_SZ)[h2];
    ax = fmaf(w, xv.x, ax);
    ay = fmaf(w, xv.y, ay);
  }
  float2 r; r.x = ax; r.y = ay;
  reinterpret_cast<float2*>(partial + ((size_t)b * 32 + ch) * H_SZ)[h2] = r;
}

// ---- out[b][h] = (1/denom_b) * sum_ch partial[b][ch][h] ----
__global__ __launch_bounds__(256) void finalize_kernel(
    const float* __restrict__ partial, const float* __restrict__ denom,
    float* __restrict__ out) {
  const int b = blockIdx.x;
  const float inv = 1.0f / denom[b];
  for (int h = threadIdx.x; h < H_SZ; h += 256) {
    float s = 0.f;
    #pragma unroll
    for (int c = 0; c < 32; ++c) s += partial[((size_t)b * 32 + c) * H_SZ + h];
    out[b * H_SZ + h] = s * inv;
  }
}

extern "C" void kernel_launch(void* const* d_in, const int* in_sizes, int n_in,
                              void* d_out, int out_size, void* d_ws, size_t ws_size,
                              hipStream_t stream) {
  const float* X = (const float*)d_in[0];   // (32,4096,512)
  const float* W = (const float*)d_in[1];   // (512,512)
  const float* v = (const float*)d_in[2];   // (512,)
  float* out = (float*)d_out;               // (32,512) fp32
  unsigned char* ws = (unsigned char*)d_ws;

  uint4* Wfrag   = (uint4*)(ws);                        // 512 KB
  float* scores  = (float*)(ws + (512u << 10));         // 512 KB (becomes u)
  float* denom   = (float*)(ws + (1024u << 10));        // 128 B
  float* partial = (float*)(ws + (1024u << 10) + 512);  // 2 MB

  prep_w_kernel<<<128, 256, 0, stream>>>(W, Wfrag);
  score_kernel<<<NROWS / 128, 256, 0, stream>>>(X, Wfrag, v, scores);
  softmax_kernel<<<B_SZ, 256, 0, stream>>>(scores, denom);
  dim3 g(32, B_SZ);
  wsum_kernel<<<g, 256, 0, stream>>>(X, scores, partial);
  finalize_kernel<<<B_SZ, 256, 0, stream>>>(partial, denom, out);
}

// Round 4
// 161.579 us; speedup vs baseline: 1.0517x; 1.0517x over previous
//
#include <hip/hip_runtime.h>
#include <hip/hip_bf16.h>

typedef __attribute__((ext_vector_type(8))) short short8;
typedef __attribute__((ext_vector_type(4))) float f32x4;

#define B_SZ 32
#define T_SZ 4096
#define H_SZ 512
#define NROWS (B_SZ * T_SZ)   // 131072

// packed fp32x2 -> bf16x2 (RNE), single v_cvt_pk_bf16_f32: a->low16, b->high16
static __device__ __forceinline__ unsigned int pack2(float a, float b) {
  unsigned int r;
  asm("v_cvt_pk_bf16_f32 %0, %1, %2" : "=v"(r) : "v"(a), "v"(b));
  return r;
}

// branch-free tanh, exact saturation at +/-inf: 1 - 2/(e^{2x}+1)
static __device__ __forceinline__ float fast_tanh(float x) {
  float e = __expf(2.0f * x);
  return 1.0f - 2.0f / (e + 1.0f);
}

// ---- W fp32 (512x512) -> bf16 in MFMA-fragment order ----
// fragment s = grow*64 + kt*4 + kslot; holds W[grow][kt*32 + kslot*8 .. +8]
// dst uint4 index = nb*1024 + kt*64 + (kslot*16 + g); a 16-g chunk = 16 KB contiguous
__global__ __launch_bounds__(256) void prep_w_kernel(
    const float* __restrict__ W, uint4* __restrict__ Wfrag) {
  int s = blockIdx.x * 256 + threadIdx.x;   // 0..32767
  int grow  = s >> 6;
  int kt    = (s >> 2) & 15;
  int kslot = s & 3;
  const float4* Wf4 = reinterpret_cast<const float4*>(W);
  float4 lo = Wf4[grow * 128 + kt * 8 + kslot * 2];
  float4 hi = Wf4[grow * 128 + kt * 8 + kslot * 2 + 1];
  uint4 u;
  u.x = pack2(lo.x, lo.y); u.y = pack2(lo.z, lo.w);
  u.z = pack2(hi.x, hi.y); u.w = pack2(hi.z, hi.w);
  int nb = grow >> 4, g = grow & 15;
  Wfrag[nb * 1024 + kt * 64 + kslot * 16 + g] = u;
}

// ---- scores[row] = sum_g v[g] * tanh( X[row,:] . W[g,:] ) ----
// 256 thr = 4 waves, wave owns 32 rows (2 A-fragsets) -> block M=128, grid 1024.
// A in registers full-K; B double-buffered 32 KB chunks (32 g) via global_load_lds.
// 8 independent MFMA chains (2 rowsets x 2 gsub x 2 kt-parity), 8-deep each.
__global__ __launch_bounds__(256, 2) void score_kernel(
    const float* __restrict__ X, const uint4* __restrict__ Wfrag,
    const float* __restrict__ v, float* __restrict__ scores) {
  __shared__ unsigned char WsB[2][32768];

  const int tid   = threadIdx.x;
  const int lane  = tid & 63;
  const int wave  = tid >> 6;
  const int frow  = lane & 15;   // A: m row / B: g col
  const int kslot = lane >> 4;
  const size_t rowbase = (size_t)blockIdx.x * 128;

  // prologue: stage chunk 0 (32 KB, 8 KB per wave) — hides under A-load/convert
  {
    const char* src = (const char*)Wfrag + wave * 8192 + lane * 16;
    unsigned char* dst = &WsB[0][wave * 8192];
    #pragma unroll
    for (int i = 0; i < 8; ++i)
      __builtin_amdgcn_global_load_lds((const unsigned int*)(src + i * 1024),
                                       (unsigned int*)(dst + i * 1024), 16, 0, 0);
  }

  // A fragments for 2 row-sets: X[arow][kt*32 + kslot*8 .. +8], bf16-packed
  short8 afrag0[16], afrag1[16];
  {
    const float4* xr0 = reinterpret_cast<const float4*>(X + (rowbase + wave * 32 + frow) * H_SZ);
    const float4* xr1 = reinterpret_cast<const float4*>(X + (rowbase + wave * 32 + 16 + frow) * H_SZ);
    #pragma unroll
    for (int kt = 0; kt < 16; ++kt) {
      float4 lo0 = xr0[kt * 8 + kslot * 2];
      float4 hi0 = xr0[kt * 8 + kslot * 2 + 1];
      union { uint4 u; short8 s; } c0;
      c0.u.x = pack2(lo0.x, lo0.y); c0.u.y = pack2(lo0.z, lo0.w);
      c0.u.z = pack2(hi0.x, hi0.y); c0.u.w = pack2(hi0.z, hi0.w);
      afrag0[kt] = c0.s;
      float4 lo1 = xr1[kt * 8 + kslot * 2];
      float4 hi1 = xr1[kt * 8 + kslot * 2 + 1];
      union { uint4 u; short8 s; } c1;
      c1.u.x = pack2(lo1.x, lo1.y); c1.u.y = pack2(lo1.z, lo1.w);
      c1.u.z = pack2(hi1.x, hi1.y); c1.u.w = pack2(hi1.z, hi1.w);
      afrag1[kt] = c1.s;
    }
  }
  __syncthreads();   // chunk 0 staged (drains vmcnt), A ready

  float red0[4] = {0.f, 0.f, 0.f, 0.f};
  float red1[4] = {0.f, 0.f, 0.f, 0.f};
  int cur = 0;
  for (int ch = 0; ch < 16; ++ch) {
    if (ch < 15) {   // stage next 32 KB chunk into the other buffer
      const char* src = (const char*)Wfrag + (size_t)(ch + 1) * 32768 + wave * 8192 + lane * 16;
      unsigned char* dst = &WsB[cur ^ 1][wave * 8192];
      #pragma unroll
      for (int i = 0; i < 8; ++i)
        __builtin_amdgcn_global_load_lds((const unsigned int*)(src + i * 1024),
                                         (unsigned int*)(dst + i * 1024), 16, 0, 0);
    }
    float vg0 = v[ch * 32 + frow];
    float vg1 = v[ch * 32 + 16 + frow];

    // 8 independent accumulator chains: [rowset][gsub][kt-parity]
    f32x4 acc[2][2][2];
    #pragma unroll
    for (int a = 0; a < 2; ++a)
      #pragma unroll
      for (int b = 0; b < 2; ++b)
        #pragma unroll
        for (int c = 0; c < 2; ++c)
          acc[a][b][c] = (f32x4){0.f, 0.f, 0.f, 0.f};

    const unsigned char* bb = &WsB[cur][lane * 16];
    #pragma unroll
    for (int kt = 0; kt < 16; ++kt) {
      short8 b0 = *reinterpret_cast<const short8*>(bb + kt * 1024);           // gsub 0
      short8 b1 = *reinterpret_cast<const short8*>(bb + 16384 + kt * 1024);   // gsub 1
      const int p = kt & 1;
      acc[0][0][p] = __builtin_amdgcn_mfma_f32_16x16x32_bf16(afrag0[kt], b0, acc[0][0][p], 0, 0, 0);
      acc[1][0][p] = __builtin_amdgcn_mfma_f32_16x16x32_bf16(afrag1[kt], b0, acc[1][0][p], 0, 0, 0);
      acc[0][1][p] = __builtin_amdgcn_mfma_f32_16x16x32_bf16(afrag0[kt], b1, acc[0][1][p], 0, 0, 0);
      acc[1][1][p] = __builtin_amdgcn_mfma_f32_16x16x32_bf16(afrag1[kt], b1, acc[1][1][p], 0, 0, 0);
    }
    // D[m][n]: n = frow (g), m = kslot*4 + reg
    #pragma unroll
    for (int r = 0; r < 4; ++r) {
      red0[r] = fmaf(vg0, fast_tanh(acc[0][0][0][r] + acc[0][0][1][r]), red0[r]);
      red0[r] = fmaf(vg1, fast_tanh(acc[0][1][0][r] + acc[0][1][1][r]), red0[r]);
      red1[r] = fmaf(vg0, fast_tanh(acc[1][0][0][r] + acc[1][0][1][r]), red1[r]);
      red1[r] = fmaf(vg1, fast_tanh(acc[1][1][0][r] + acc[1][1][1][r]), red1[r]);
    }

    __syncthreads();   // all waves done reading cur; stage into cur^1 drained
    cur ^= 1;
  }

  // reduce over the 16 g-lanes (frow) within each kslot group
  #pragma unroll
  for (int r = 0; r < 4; ++r) {
    #pragma unroll
    for (int d = 1; d < 16; d <<= 1) {
      red0[r] += __shfl_xor(red0[r], d);
      red1[r] += __shfl_xor(red1[r], d);
    }
  }
  if (frow == 0) {
    float* sp = scores + rowbase + wave * 32 + kslot * 4;
    sp[0]  = red0[0]; sp[1]  = red0[1]; sp[2]  = red0[2]; sp[3]  = red0[3];
    sp[16] = red1[0]; sp[17] = red1[1]; sp[18] = red1[2]; sp[19] = red1[3];
  }
}

// ---- per-b softmax stats; rewrites scores in place with unnormalized exp ----
__global__ __launch_bounds__(256) void softmax_kernel(
    float* __restrict__ scores, float* __restrict__ denom) {
  const int b = blockIdx.x;
  float* s = scores + b * T_SZ;
  const int tid = threadIdx.x;
  __shared__ float redm[4], reds[4];

  float m = -1e30f;
  for (int t = tid; t < T_SZ; t += 256) m = fmaxf(m, s[t]);
  #pragma unroll
  for (int d = 1; d < 64; d <<= 1) m = fmaxf(m, __shfl_xor(m, d));
  if ((tid & 63) == 0) redm[tid >> 6] = m;
  __syncthreads();
  m = fmaxf(fmaxf(redm[0], redm[1]), fmaxf(redm[2], redm[3]));

  float sum = 0.f;
  for (int t = tid; t < T_SZ; t += 256) {
    float u = __expf(s[t] - m);
    s[t] = u;
    sum += u;
  }
  #pragma unroll
  for (int d = 1; d < 64; d <<= 1) sum += __shfl_xor(sum, d);
  if ((tid & 63) == 0) reds[tid >> 6] = sum;
  __syncthreads();
  if (tid == 0) denom[b] = reds[0] + reds[1] + reds[2] + reds[3];
}

// ---- partial[b][ch][h] = sum_{t in chunk} u_t * x[b,t,h] ----
__global__ __launch_bounds__(256) void wsum_kernel(
    const float* __restrict__ X, const float* __restrict__ u,
    float* __restrict__ partial) {
  const int ch = blockIdx.x;   // 32 chunks of 128 t
  const int b  = blockIdx.y;   // 32
  const float* xb = X + ((size_t)b * T_SZ + ch * 128) * H_SZ;
  const float* ub = u + b * T_SZ + ch * 128;
  const int h2 = threadIdx.x;  // float2 index
  float ax = 0.f, ay = 0.f;
  for (int tt = 0; tt < 128; ++tt) {
    float w = ub[tt];
    float2 xv = reinterpret_cast<const float2*>(xb + (size_t)tt * H_SZ)[h2];
    ax = fmaf(w, xv.x, ax);
    ay = fmaf(w, xv.y, ay);
  }
  float2 r; r.x = ax; r.y = ay;
  reinterpret_cast<float2*>(partial + ((size_t)b * 32 + ch) * H_SZ)[h2] = r;
}

// ---- out[b][h] = (1/denom_b) * sum_ch partial[b][ch][h] ----
__global__ __launch_bounds__(256) void finalize_kernel(
    const float* __restrict__ partial, const float* __restrict__ denom,
    float* __restrict__ out) {
  const int b = blockIdx.x;
  const float inv = 1.0f / denom[b];
  for (int h = threadIdx.x; h < H_SZ; h += 256) {
    float s = 0.f;
    #pragma unroll
    for (int c = 0; c < 32; ++c) s += partial[((size_t)b * 32 + c) * H_SZ + h];
    out[b * H_SZ + h] = s * inv;
  }
}

extern "C" void kernel_launch(void* const* d_in, const int* in_sizes, int n_in,
                              void* d_out, int out_size, void* d_ws, size_t ws_size,
                              hipStream_t stream) {
  const float* X = (const float*)d_in[0];   // (32,4096,512)
  const float* W = (const float*)d_in[1];   // (512,512)
  const float* v = (const float*)d_in[2];   // (512,)
  float* out = (float*)d_out;               // (32,512) fp32
  unsigned char* ws = (unsigned char*)d_ws;

  uint4* Wfrag   = (uint4*)(ws);                        // 512 KB
  float* scores  = (float*)(ws + (512u << 10));         // 512 KB (becomes u)
  float* denom   = (float*)(ws + (1024u << 10));        // 128 B
  float* partial = (float*)(ws + (1024u << 10) + 512);  // 2 MB

  prep_w_kernel<<<128, 256, 0, stream>>>(W, Wfrag);
  score_kernel<<<NROWS / 128, 256, 0, stream>>>(X, Wfrag, v, scores);
  softmax_kernel<<<B_SZ, 256, 0, stream>>>(scores, denom);
  dim3 g(32, B_SZ);
  wsum_kernel<<<g, 256, 0, stream>>>(X, scores, partial);
  finalize_kernel<<<B_SZ, 256, 0, stream>>>(partial, denom, out);
}